// Round 1
// 179.026 us; speedup vs baseline: 1.1122x; 1.1122x over previous
//
#include <hip/hip_runtime.h>
#include <hip/hip_bf16.h>
#include <math.h>

// DigitCaps routing. PROVEN: P/W/out all FP32; MFMA hi/lo split path correct
// (round 7: PASS absmax 1.95e-3). Round 8: agree -> MFMA (tgemm+reduce_bc),
// sgemm 512thr 8-way split-K, v kept only in transposed hi/lo form.
// Round 9 (this): fuse tgemm+reduce_bc into agree_kernel (G stays in LDS,
// 576 blocks x 4 waves split-K over b), merge split_p+split_w into one launch.
//   P [256][9216] f32, W [1152][10][16][8] f32, out v [256][10][16] f32.

typedef __bf16 bf16x8 __attribute__((ext_vector_type(8)));
typedef float v4f __attribute__((ext_vector_type(4)));

__device__ __forceinline__ float b2f(unsigned short u) {
    return __uint_as_float(((unsigned)u) << 16);
}
__device__ __forceinline__ unsigned short f2b(float f) {   // RNE, finite only
    unsigned x = __float_as_uint(f);
    return (unsigned short)((x + 0x7FFFu + ((x >> 16) & 1u)) >> 16);
}
__device__ __forceinline__ void split4(float4 x, unsigned short* h, unsigned short* l) {
    const float* xf = (const float*)&x;
    #pragma unroll
    for (int i = 0; i < 4; ++i) {
        h[i] = f2b(xf[i]);
        l[i] = f2b(xf[i] - b2f(h[i]));
    }
}
__device__ __forceinline__ uint2 pack4(const unsigned short* s) {
    uint2 w;
    w.x = s[0] | ((unsigned)s[1] << 16);
    w.y = s[2] | ((unsigned)s[3] << 16);
    return w;
}

// ---- merged split: blocks [0,576) split P (64b x 64k tile each);
//      blocks [576,2016) split W elementwise.
__global__ __launch_bounds__(256) void split_pw_kernel(
    const float4* __restrict__ P4, uint2* __restrict__ Ph, uint2* __restrict__ Pl,
    uint4* __restrict__ Pth, uint4* __restrict__ Ptl,
    const float4* __restrict__ W4, uint2* __restrict__ Wh, uint2* __restrict__ Wl)
{
    __shared__ unsigned short ldsH[64 * 72];
    __shared__ unsigned short ldsL[64 * 72];
    const int tid = threadIdx.x;

    if (blockIdx.x >= 576) {   // ---- W path ----
        const int idx = (blockIdx.x - 576) * 256 + tid;    // 0..368639
        unsigned short h[4], l[4];
        split4(W4[idx], h, l);
        Wh[idx] = pack4(h);
        Wl[idx] = pack4(l);
        return;
    }

    // ---- P path ----
    const int b0 = (blockIdx.x & 3) * 64;
    const int k0 = (blockIdx.x >> 2) * 64;
    #pragma unroll
    for (int j = 0; j < 4; ++j) {
        int idx = tid + j * 256;              // 0..1023
        int row = idx >> 4, col4 = idx & 15;  // b-local, k/4-local
        int g = (b0 + row) * 2304 + (k0 >> 2) + col4;
        unsigned short h[4], l[4];
        split4(P4[g], h, l);
        Ph[g] = pack4(h);
        Pl[g] = pack4(l);
        #pragma unroll
        for (int i = 0; i < 4; ++i) {
            ldsH[(col4 * 4 + i) * 72 + row] = h[i];
            ldsL[(col4 * 4 + i) * 72 + row] = l[i];
        }
    }
    __syncthreads();
    #pragma unroll
    for (int j = 0; j < 2; ++j) {
        int idx = tid + j * 256;              // 0..511
        int krow = idx >> 3, bcol = idx & 7;
        unsigned short h[8], l[8];
        #pragma unroll
        for (int i = 0; i < 8; ++i) {
            h[i] = ldsH[krow * 72 + bcol * 8 + i];
            l[i] = ldsL[krow * 72 + bcol * 8 + i];
        }
        uint4 wh, wl;
        wh.x = h[0] | ((unsigned)h[1] << 16); wh.y = h[2] | ((unsigned)h[3] << 16);
        wh.z = h[4] | ((unsigned)h[5] << 16); wh.w = h[6] | ((unsigned)h[7] << 16);
        wl.x = l[0] | ((unsigned)l[1] << 16); wl.y = l[2] | ((unsigned)l[3] << 16);
        wl.z = l[4] | ((unsigned)l[5] << 16); wl.w = l[6] | ((unsigned)l[7] << 16);
        Pth[(size_t)(k0 + krow) * 32 + (b0 >> 3) + bcol] = wh;
        Ptl[(size_t)(k0 + krow) * 32 + (b0 >> 3) + bcol] = wl;
    }
}

// ---- MFMA s-GEMM + fused squash (round-7-proven maps; 512 thr, K/8 per wave).
// Writes v transposed hi/lo (vt[cd][b]) for agree A; last iter writes outb.
__global__ __launch_bounds__(512) void sgemm_kernel(
    const uint4* __restrict__ Ah, const uint4* __restrict__ Al,
    const uint4* __restrict__ Bh, const uint4* __restrict__ Bl,
    uint2* __restrict__ vth, uint2* __restrict__ vtl,
    float* __restrict__ outb, int uniform, int last)
{
    __shared__ float comb[8][64][4];
    const int tid = threadIdx.x;
    const int wave = tid >> 6, lane = tid & 63;
    const int lm = lane & 15, q = lane >> 4;
    const int c = blockIdx.x / 16, b0 = (blockIdx.x % 16) * 16;

    const uint4* Ahp = Ah + (size_t)(b0 + lm) * 1152 + q;
    const uint4* Alp = Al + (size_t)(b0 + lm) * 1152 + q;
    const uint4* Bhp = Bh + ((size_t)q * 10 + c) * 16 + lm;
    const uint4* Blp = Bl + ((size_t)q * 10 + c) * 16 + lm;

    v4f acc = {0.f, 0.f, 0.f, 0.f};
    const int kk0 = wave * 36;
    for (int kk = kk0; kk < kk0 + 36; ++kk) {
        bf16x8 ah = __builtin_bit_cast(bf16x8, Ahp[(size_t)kk * 4]);
        bf16x8 al = __builtin_bit_cast(bf16x8, Alp[(size_t)kk * 4]);
        bf16x8 bh = __builtin_bit_cast(bf16x8, Bhp[(size_t)kk * 640]);
        bf16x8 bl = __builtin_bit_cast(bf16x8, Blp[(size_t)kk * 640]);
        acc = __builtin_amdgcn_mfma_f32_16x16x32_bf16(ah, bh, acc, 0, 0, 0);
        acc = __builtin_amdgcn_mfma_f32_16x16x32_bf16(ah, bl, acc, 0, 0, 0);
        acc = __builtin_amdgcn_mfma_f32_16x16x32_bf16(al, bh, acc, 0, 0, 0);
    }
    #pragma unroll
    for (int r = 0; r < 4; ++r) comb[wave][lane][r] = acc[r];
    __syncthreads();
    if (wave == 0) {
        float s[4], sq[4];
        #pragma unroll
        for (int r = 0; r < 4; ++r) {
            s[r] = 0.f;
            #pragma unroll
            for (int w = 0; w < 8; ++w) s[r] += comb[w][lane][r];
            if (uniform) s[r] *= 0.1f;
            sq[r] = s[r] * s[r];
        }
        #pragma unroll
        for (int m = 1; m < 16; m <<= 1) {
            #pragma unroll
            for (int r = 0; r < 4; ++r) sq[r] += __shfl_xor(sq[r], m);
        }
        float v[4];
        #pragma unroll
        for (int r = 0; r < 4; ++r) {
            const float n = sq[r];
            v[r] = s[r] * sqrtf(n) / (1.0f + n);
        }
        if (!last) {
            unsigned short h[4], l[4];
            #pragma unroll
            for (int r = 0; r < 4; ++r) {
                h[r] = f2b(v[r]);
                l[r] = f2b(v[r] - b2f(h[r]));
            }
            const int o = (c * 16 + lm) * 64 + (b0 >> 2) + q;   // uint2 units
            vth[o] = pack4(h);
            vtl[o] = pack4(l);
        } else {
            #pragma unroll
            for (int r = 0; r < 4; ++r)
                outb[((b0 + q * 4 + r) * 10 + c) * 16 + lm] = v[r];
        }
    }
}

// ---- agree: fused tgemm + reduce_bc. One block per 16-ri tile (n0 = bid*16,
// covering r = 2*bid, 2*bid+1). 4 waves split K=256 (b) -> 2 kk-steps each;
// partials summed via LDS; G kept in LDS; then the proven reduce_bc logic
// runs on the two r-rows with 128 threads each; emits Bc hi/lo + b_log.
__global__ __launch_bounds__(256) void agree_kernel(
    const uint4* __restrict__ vth, const uint4* __restrict__ vtl,
    const uint4* __restrict__ Pth, const uint4* __restrict__ Ptl,
    const float* __restrict__ Wf, float* __restrict__ b_log,
    unsigned short* __restrict__ Bh, unsigned short* __restrict__ Bl, int first)
{
    __shared__ float comb2[40][4][64];   // [mt*4+reg][wave][lane] - conflict-free
    __shared__ float G_lds[160][18];     // [cd][ri-local], pad 16->18
    __shared__ float part[4][10];
    __shared__ float cl[2][10];
    const int tid = threadIdx.x;
    const int wave = tid >> 6, lane = tid & 63;
    const int lm = lane & 15, q = lane >> 4;
    const int n0 = blockIdx.x * 16;

    // ---- K-split tgemm: wave handles kk in {2*wave, 2*wave+1} ----
    v4f acc[10];
    #pragma unroll
    for (int mt = 0; mt < 10; ++mt) acc[mt] = (v4f){0.f, 0.f, 0.f, 0.f};
    #pragma unroll
    for (int kx = 0; kx < 2; ++kx) {
        const int kk = wave * 2 + kx;
        bf16x8 bh_ = __builtin_bit_cast(bf16x8, Pth[(size_t)(n0 + lm) * 32 + kk * 4 + q]);
        bf16x8 bl_ = __builtin_bit_cast(bf16x8, Ptl[(size_t)(n0 + lm) * 32 + kk * 4 + q]);
        #pragma unroll
        for (int mt = 0; mt < 10; ++mt) {
            bf16x8 ah = __builtin_bit_cast(bf16x8, vth[(size_t)(mt * 16 + lm) * 32 + kk * 4 + q]);
            bf16x8 al = __builtin_bit_cast(bf16x8, vtl[(size_t)(mt * 16 + lm) * 32 + kk * 4 + q]);
            acc[mt] = __builtin_amdgcn_mfma_f32_16x16x32_bf16(ah, bh_, acc[mt], 0, 0, 0);
            acc[mt] = __builtin_amdgcn_mfma_f32_16x16x32_bf16(ah, bl_, acc[mt], 0, 0, 0);
            acc[mt] = __builtin_amdgcn_mfma_f32_16x16x32_bf16(al, bh_, acc[mt], 0, 0, 0);
        }
    }
    #pragma unroll
    for (int mt = 0; mt < 10; ++mt)
        #pragma unroll
        for (int r = 0; r < 4; ++r)
            comb2[mt * 4 + r][wave][lane] = acc[mt][r];
    __syncthreads();
    // ---- sum wave partials -> G_lds. Wave w owns c40 = w*10 .. w*10+9 ----
    #pragma unroll
    for (int j = 0; j < 10; ++j) {
        const int c40 = wave * 10 + j;
        float s_ = comb2[c40][0][lane] + comb2[c40][1][lane]
                 + comb2[c40][2][lane] + comb2[c40][3][lane];
        const int mt = c40 >> 2, reg = c40 & 3;
        G_lds[mt * 16 + q * 4 + reg][lm] = s_;     // G[cd][ri = n0+lm]
    }
    __syncthreads();

    // ---- reduce_bc phase (proven logic; 128 threads per r-row) ----
    const int rl = tid >> 7;        // 0..1 -> which r this half-block owns
    const int t = tid & 127;        // d*8+i
    const int r = (n0 >> 3) + rl;
    const int wid2 = tid >> 6;      // 0..3

    float wv[10], a[10];
    #pragma unroll
    for (int c = 0; c < 10; ++c) {
        wv[c] = Wf[((size_t)r * 10 + c) * 128 + t];
        float g = G_lds[c * 16 + (t >> 3)][rl * 8 + (t & 7)];
        a[c] = wv[c] * g;
    }
    #pragma unroll
    for (int m = 1; m < 64; m <<= 1) {
        #pragma unroll
        for (int c = 0; c < 10; ++c) a[c] += __shfl_xor(a[c], m);
    }
    if (lane == 0) {
        #pragma unroll
        for (int c = 0; c < 10; ++c) part[wid2][c] = a[c];
    }
    __syncthreads();
    if (t < 10) {    // threads 0..9 (rl=0) and 128..137 (rl=1)
        float s_ = (part[rl * 2][t] + part[rl * 2 + 1][t]) * (1.0f / 256.0f);
        float bn = (first ? 0.f : b_log[r * 10 + t]) + s_;
        b_log[r * 10 + t] = bn;
        part[rl * 2][t] = bn;            // reuse as softmax scratch
    }
    __syncthreads();
    if (t < 10) {
        float mx = part[rl * 2][0];
        #pragma unroll
        for (int j = 1; j < 10; ++j) mx = fmaxf(mx, part[rl * 2][j]);
        float den = 0.f;
        #pragma unroll
        for (int j = 0; j < 10; ++j) den += __expf(part[rl * 2][j] - mx);
        cl[rl][t] = __expf(part[rl * 2][t] - mx) / den;
    }
    __syncthreads();
    #pragma unroll
    for (int c = 0; c < 10; ++c) {
        float x = cl[rl][c] * wv[c];
        unsigned short h = f2b(x);
        Bh[((size_t)r * 10 + c) * 128 + t] = h;
        Bl[((size_t)r * 10 + c) * 128 + t] = f2b(x - b2f(h));
    }
}

extern "C" void kernel_launch(void* const* d_in, const int* in_sizes, int n_in,
                              void* d_out, int out_size, void* d_ws, size_t ws_size,
                              hipStream_t stream)
{
    const float4* P4 = (const float4*)d_in[0];
    const float4* W4 = (const float4*)d_in[1];
    char* wsb = (char*)d_ws;
    // BYTE offsets (audited, all 16B-aligned):
    float* b_log = (float*)(wsb + 0);              // 46080 B
    uint2* vth   = (uint2*)(wsb + 131072);         // 81920 B
    uint2* vtl   = (uint2*)(wsb + 262144);         // 81920 B
    uint2* Ph    = (uint2*)(wsb + 393216);         // 4718592 B
    uint2* Pl    = (uint2*)(wsb + 5242880);        // 4718592 B
    uint4* Pth   = (uint4*)(wsb + 10485760);       // 4718592 B
    uint4* Ptl   = (uint4*)(wsb + 15728640);       // 4718592 B
    uint2* Wh    = (uint2*)(wsb + 20971520);       // 2949120 B
    uint2* Wl    = (uint2*)(wsb + 25165824);       // 2949120 B
    unsigned short* Bh = (unsigned short*)(wsb + 29360128);  // 2949120 B
    unsigned short* Bl = (unsigned short*)(wsb + 33554432);  // 2949120 B
    float* outb  = (float*)d_out;
    const float* Wf = (const float*)W4;

    split_pw_kernel<<<2016, 256, 0, stream>>>(P4, Ph, Pl, Pth, Ptl, W4, Wh, Wl);

    // iter 0: B = W, uniform c = 0.1 post-MFMA
    sgemm_kernel<<<160, 512, 0, stream>>>((const uint4*)Ph, (const uint4*)Pl,
                                          (const uint4*)Wh, (const uint4*)Wl,
                                          vth, vtl, outb, 1, 0);
    agree_kernel<<<576, 256, 0, stream>>>((const uint4*)vth, (const uint4*)vtl,
                                          Pth, Ptl, Wf, b_log, Bh, Bl, 1);
    // iter 1
    sgemm_kernel<<<160, 512, 0, stream>>>((const uint4*)Ph, (const uint4*)Pl,
                                          (const uint4*)Bh, (const uint4*)Bl,
                                          vth, vtl, outb, 0, 0);
    agree_kernel<<<576, 256, 0, stream>>>((const uint4*)vth, (const uint4*)vtl,
                                          Pth, Ptl, Wf, b_log, Bh, Bl, 0);
    // iter 2 -> d_out
    sgemm_kernel<<<160, 512, 0, stream>>>((const uint4*)Ph, (const uint4*)Pl,
                                          (const uint4*)Bh, (const uint4*)Bl,
                                          vth, vtl, outb, 0, 1);
}